// Round 2
// baseline (12420.178 us; speedup 1.0000x reference)
//
#include <hip/hip_runtime.h>

// ---------------------------------------------------------------------------
// GRU forecaster: B=32, T=2048, I=256, H=512, L=2, O=64
// Phases per chunk: GEMM(xi chunk, fused fp32->bf16 cast) -> cooperative scan.
// Scan: 16 clusters x 16 WGs (1 WG/CU, 96KB LDS-resident weight slice),
// per-step h exchange via epoch-stamped 8B agent-scope atomics.
// Chunked over T so workspace adapts to ws_size (xi chunk is the big buffer).
// ---------------------------------------------------------------------------

typedef unsigned int  u32;
typedef unsigned short u16;
typedef unsigned long long u64;
typedef float v4f __attribute__((ext_vector_type(4)));
typedef short v8s __attribute__((ext_vector_type(8)));

__device__ __forceinline__ u16 f2bf(float f) {
    u32 u = __float_as_uint(f);
    u32 r = (u + 0x7fffu + ((u >> 16) & 1u)) >> 16;
    return (u16)r;
}
__device__ __forceinline__ float bf2f(u16 b) {
    return __uint_as_float(((u32)b) << 16);
}
__device__ __forceinline__ void unpack8(uint4 d, float* o) {
    o[0] = __uint_as_float(d.x << 16); o[1] = __uint_as_float(d.x & 0xffff0000u);
    o[2] = __uint_as_float(d.y << 16); o[3] = __uint_as_float(d.y & 0xffff0000u);
    o[4] = __uint_as_float(d.z << 16); o[5] = __uint_as_float(d.z & 0xffff0000u);
    o[6] = __uint_as_float(d.w << 16); o[7] = __uint_as_float(d.w & 0xffff0000u);
}

// --------------------------- prep kernels ----------------------------------

// src fp32 [R][C] -> dst bf16 [C][R]  (32x32 tiles)
__global__ __launch_bounds__(256) void transpose_cast(const float* __restrict__ src,
                                                      u16* __restrict__ dst,
                                                      int R, int C) {
    __shared__ u16 tile[32][33];
    int c0 = blockIdx.x * 32, r0 = blockIdx.y * 32;
    int t = threadIdx.x;
    {
        int rl = t >> 3, cl4 = (t & 7) * 4;
        float4 v = *(const float4*)&src[(size_t)(r0 + rl) * C + c0 + cl4];
        tile[rl][cl4 + 0] = f2bf(v.x);
        tile[rl][cl4 + 1] = f2bf(v.y);
        tile[rl][cl4 + 2] = f2bf(v.z);
        tile[rl][cl4 + 3] = f2bf(v.w);
    }
    __syncthreads();
    {
        int cl = t >> 3, rl4 = (t & 7) * 4;
        uint2 o;
        o.x = (u32)tile[rl4 + 0][cl] | ((u32)tile[rl4 + 1][cl] << 16);
        o.y = (u32)tile[rl4 + 2][cl] | ((u32)tile[rl4 + 3][cl] << 16);
        *(uint2*)&dst[(size_t)(c0 + cl) * R + r0 + rl4] = o;
    }
}

// Wh fp32 [512][1536] -> packed bf16 entries: entry(k8 in [0,64), j in [0,512))
// = 48B: 3 gates x 8 bf16 (k = k8*8 .. +8), gate g col = g*512 + j.
__global__ __launch_bounds__(256) void pack_wh(const float* __restrict__ Wh,
                                               uint4* __restrict__ dst) {
    int id = blockIdx.x * 256 + threadIdx.x;   // < 98304
    int jl = id & 511;
    int g  = (id >> 9) % 3;
    int k8 = id / 1536;
    u32 d[4];
#pragma unroll
    for (int p = 0; p < 4; ++p) {
        float w0 = Wh[(size_t)(k8 * 8 + 2 * p) * 1536 + g * 512 + jl];
        float w1 = Wh[(size_t)(k8 * 8 + 2 * p + 1) * 1536 + g * 512 + jl];
        d[p] = (u32)f2bf(w0) | ((u32)f2bf(w1) << 16);
    }
    uint4 o; o.x = d[0]; o.y = d[1]; o.z = d[2]; o.w = d[3];
    dst[(size_t)(k8 * 512 + jl) * 3 + g] = o;
}

// ---------------- GEMM: xi_chunk = A_rows @ Bt^T + bias -> bf16 -------------
// A: logical rows (b*2048 + t0 + tl), fp32 (layer0) or bf16 (layer1), K cols.
// Bt: [1536][K] bf16. C: [32*Tc][1536] bf16, row m = b*Tc + tl (chunk-local).
template <int K, bool AF32>
__global__ __launch_bounds__(256) void gemm_xi(const void* __restrict__ Ap,
                                               const u16* __restrict__ Bt,
                                               const float* __restrict__ bias,
                                               u16* __restrict__ C,
                                               int t0, int lgTc) {
    __shared__ u16 As[64 * 40];   // 64 rows x 32 k, row stride 40 (pad)
    __shared__ u16 Bs[64 * 40];
    const int tid = threadIdx.x;
    const int n0 = blockIdx.x * 64;
    const int m0 = blockIdx.y * 64;
    const int row = tid >> 2, koff = (tid & 3) * 8;
    const int lane = tid & 63, w = tid >> 6;
    // source row for A staging
    const int m = m0 + row;
    const int b = m >> lgTc;
    const int tl = m & ((1 << lgTc) - 1);
    const size_t srow = ((size_t)b << 11) + (size_t)(t0 + tl);
    v4f acc[4];
#pragma unroll
    for (int i = 0; i < 4; ++i) acc[i] = (v4f){0.f, 0.f, 0.f, 0.f};

    for (int k0 = 0; k0 < K; k0 += 32) {
        if (AF32) {
            const float* A = (const float*)Ap;
            float4 v0 = *(const float4*)&A[srow * K + k0 + koff];
            float4 v1 = *(const float4*)&A[srow * K + k0 + koff + 4];
            uint4 o;
            o.x = (u32)f2bf(v0.x) | ((u32)f2bf(v0.y) << 16);
            o.y = (u32)f2bf(v0.z) | ((u32)f2bf(v0.w) << 16);
            o.z = (u32)f2bf(v1.x) | ((u32)f2bf(v1.y) << 16);
            o.w = (u32)f2bf(v1.z) | ((u32)f2bf(v1.w) << 16);
            *(uint4*)&As[row * 40 + koff] = o;
        } else {
            const u16* A = (const u16*)Ap;
            *(uint4*)&As[row * 40 + koff] =
                *(const uint4*)&A[srow * K + k0 + koff];
        }
        *(uint4*)&Bs[row * 40 + koff] =
            *(const uint4*)&Bt[(size_t)(n0 + row) * K + k0 + koff];
        __syncthreads();
        v8s a = *(const v8s*)&As[(w * 16 + (lane & 15)) * 40 + (lane >> 4) * 8];
#pragma unroll
        for (int nt = 0; nt < 4; ++nt) {
            v8s bm = *(const v8s*)&Bs[(nt * 16 + (lane & 15)) * 40 + (lane >> 4) * 8];
            acc[nt] = __builtin_amdgcn_mfma_f32_16x16x32_bf16(a, bm, acc[nt], 0, 0, 0);
        }
        __syncthreads();
    }
#pragma unroll
    for (int nt = 0; nt < 4; ++nt) {
        int col = n0 + nt * 16 + (lane & 15);
        float bv = bias[col];
#pragma unroll
        for (int rI = 0; rI < 4; ++rI) {
            int rowm = m0 + w * 16 + (lane >> 4) * 4 + rI;
            C[(size_t)rowm * 1536 + col] = f2bf(acc[nt][rI] + bv);
        }
    }
}

// --------------------------- GRU scan (cooperative) -------------------------
// grid = 256 x 512. cluster = blockIdx & 15, member = blockIdx >> 4.
// Cluster c owns batches {2c, 2c+1}; member m owns hidden units [32m, 32m+32).
// Processes steps [t0, t0+Tc); state persists via hstate (fp32 h) + Hbuf.
__global__ __launch_bounds__(512) void gru_scan(const u16* __restrict__ xi,
                                                const uint4* __restrict__ Whp,
                                                const float* __restrict__ bhn,
                                                u64* __restrict__ Hbuf,
                                                u32* __restrict__ hseq,
                                                float* __restrict__ h1last,
                                                float* __restrict__ hstate,
                                                int t0, int Tc, int layer0) {
    __shared__ uint4 LWp4[6144];                 // 96KB weight slice
    __shared__ __align__(16) u32 Lh[512];        // h as bf16 pairs [2][256]
    __shared__ float LRow[8 * 33 * 6];           // per-wave partials

    const int tid = threadIdx.x;
    const int wg = blockIdx.x;
    const int cluster = wg & 15;
    const int member = wg >> 4;

    // stage weight slice: per k8-row, entries [member*32, +32), 96 uint4/row
    {
        int k8 = tid >> 3, part = tid & 7;
        const uint4* src = Whp + (size_t)(k8 * 512 + member * 32) * 3 + part * 12;
        uint4* dst = LWp4 + k8 * 96 + part * 12;
#pragma unroll
        for (int i = 0; i < 12; ++i) dst[i] = src[i];
    }

    const int s = tid >> 5, j = tid & 31;
    const int lane = tid & 63, w = tid >> 6;
    const int b_f = tid >> 5;                 // finalize batch (tid<64 only)
    const int jj = member * 32 + j;
    const int bg = cluster * 2 + b_f;
    float hprev = 0.f;
    float bhnv = (tid < 64) ? bhn[jj] : 0.f;

    if (t0 == 0) {
        Lh[tid] = 0;   // h_{-1} = 0
    } else {
        // reload h_{t0-1} pairs from previous chunk's parity buffer
        Lh[tid] = (u32)Hbuf[(size_t)(cluster * 2 + ((t0 - 1) & 1)) * 512 + tid];
        if (tid < 64) hprev = hstate[bg * 512 + jj];
    }
    __syncthreads();

    for (int t = t0; t < t0 + Tc; ++t) {
        // prefetch xi for finalize (independent of h)
        u16 rx = 0, rz = 0, rn = 0;
        if (tid < 64) {
            const u16* xp = xi + ((size_t)bg * Tc + (t - t0)) * 1536 + jj;
            rx = xp[0]; rz = xp[512]; rn = xp[1024];
        }
        // ---- partial dots: thread (s,j): k in [32s, 32s+32), 3 gates x 2 batch
        float acc[3][2];
#pragma unroll
        for (int g = 0; g < 3; ++g) { acc[g][0] = 0.f; acc[g][1] = 0.f; }
#pragma unroll
        for (int q = 0; q < 4; ++q) {
            int k8 = s * 4 + q;
            uint4 h0 = *(const uint4*)&Lh[k8 * 4];
            uint4 h1 = *(const uint4*)&Lh[256 + k8 * 4];
            float h0v[8], h1v[8];
            unpack8(h0, h0v); unpack8(h1, h1v);
            const uint4* e = &LWp4[(k8 * 32 + j) * 3];
#pragma unroll
            for (int g = 0; g < 3; ++g) {
                float wv[8];
                unpack8(e[g], wv);
#pragma unroll
                for (int i = 0; i < 8; ++i) {
                    acc[g][0] += wv[i] * h0v[i];
                    acc[g][1] += wv[i] * h1v[i];
                }
            }
        }
        // ---- intra-wave k-pair reduce, stash per-wave partials
#pragma unroll
        for (int g = 0; g < 3; ++g) {
            acc[g][0] += __shfl_xor(acc[g][0], 32);
            acc[g][1] += __shfl_xor(acc[g][1], 32);
        }
        if (lane < 32) {
            float* o = &LRow[(w * 33 + lane) * 6];
            o[0] = acc[0][0]; o[1] = acc[1][0]; o[2] = acc[2][0];
            o[3] = acc[0][1]; o[4] = acc[1][1]; o[5] = acc[2][1];
        }
        __syncthreads();

        u64* slot = Hbuf + (size_t)(cluster * 2 + (t & 1)) * 512;
        // ---- finalize: wave 0 = (b in 2) x (j in 32)
        if (tid < 64) {
            float hr = 0.f, hz = 0.f, hn = 0.f;
#pragma unroll
            for (int ww = 0; ww < 8; ++ww) {
                const float* o = &LRow[(ww * 33 + j) * 6 + b_f * 3];
                hr += o[0]; hz += o[1]; hn += o[2];
            }
            float xrv = bf2f(rx), xzv = bf2f(rz), xnv = bf2f(rn);
            float r = 1.f / (1.f + __expf(-(xrv + hr)));
            float z = 1.f / (1.f + __expf(-(xzv + hz)));
            float nx = xnv + r * (hn + bhnv);
            float n = 1.f - 2.f / (__expf(2.f * nx) + 1.f);   // tanh (saturating-safe)
            float hnew = (1.f - z) * n + z * hprev;
            hprev = hnew;                                     // fp32 memory path
            u32 hb = (u32)f2bf(hnew);
            u32 nb = __shfl_down(hb, 1);
            if ((j & 1) == 0) {
                u32 pair = hb | (nb << 16);
                u64 qv = (u64)pair | ((u64)(u32)(t + 1) << 32);
                __hip_atomic_store(&slot[b_f * 256 + (jj >> 1)], qv,
                                   __ATOMIC_RELAXED, __HIP_MEMORY_SCOPE_AGENT);
                if (layer0)
                    hseq[((size_t)bg * 2048 + t) * 256 + (jj >> 1)] = pair;
            }
            if (!layer0 && t == 2047) h1last[bg * 512 + jj] = hnew;
        }
        // ---- poll own qword (data IS the flag), fill Lh with h_t
        {
            const u32 target = (u32)(t + 1);
            u64* myq = &slot[tid];
            u64 qv = 0;
            for (int it = 0; it < 4000000; ++it) {
                qv = __hip_atomic_load(myq, __ATOMIC_RELAXED, __HIP_MEMORY_SCOPE_AGENT);
                if ((u32)(qv >> 32) == target) break;
                __builtin_amdgcn_s_sleep(1);
            }
            Lh[tid] = (u32)qv;
        }
        __syncthreads();
    }
    if (tid < 64) hstate[bg * 512 + jj] = hprev;   // persist for next chunk
}

// --------------------------- final FC --------------------------------------
__global__ __launch_bounds__(64) void final_fc(const float* __restrict__ h1,
                                               const float* __restrict__ Wfc,
                                               const float* __restrict__ bfc,
                                               float* __restrict__ out) {
    int b = blockIdx.x, o = threadIdx.x;
    float acc = bfc[o];
    for (int k = 0; k < 512; ++k) acc += h1[b * 512 + k] * Wfc[k * 64 + o];
    out[b * 64 + o] = acc;
}

// --------------------------- launch ----------------------------------------

extern "C" void kernel_launch(void* const* d_in, const int* in_sizes, int n_in,
                              void* d_out, int out_size, void* d_ws, size_t ws_size,
                              hipStream_t stream) {
    const float* x    = (const float*)d_in[0];
    const float* Wi0  = (const float*)d_in[1];
    const float* bi0  = (const float*)d_in[2];
    const float* Wh0  = (const float*)d_in[3];
    const float* bhn0 = (const float*)d_in[4];
    const float* Wi1  = (const float*)d_in[5];
    const float* bi1  = (const float*)d_in[6];
    const float* Wh1  = (const float*)d_in[7];
    const float* bhn1 = (const float*)d_in[8];
    const float* Wfc  = (const float*)d_in[9];
    const float* bfc  = (const float*)d_in[10];
    float* out = (float*)d_out;
    (void)in_sizes; (void)n_in; (void)out_size;

    // ---- workspace layout (256B aligned), xi chunk buffer last/adaptive ----
    char* ws = (char*)d_ws;
    size_t off = 0;
    auto take = [&](size_t bytes) -> char* {
        char* p = ws + off;
        off = (off + bytes + 255) & ~(size_t)255;
        return p;
    };
    u16*  Wi0t  = (u16*)take(1536 * 256 * 2);       //   786,432
    u16*  Wi1t  = (u16*)take(1536 * 512 * 2);       // 1,572,864
    uint4* Wh0p = (uint4*)take(98304 * 16);         // 1,572,864
    uint4* Wh1p = (uint4*)take(98304 * 16);         // 1,572,864
    u64*  Hb0   = (u64*)take(32 * 512 * 8);         //   131,072
    u64*  Hb1   = (u64*)take(32 * 512 * 8);         //   131,072
    float* hstate = (float*)take(32 * 512 * 4);     //    65,536
    float* h1last = (float*)take(32 * 512 * 4);     //    65,536
    u16*  h0seq = (u16*)take((size_t)32 * 2048 * 512 * 2);   // 67,108,864
    size_t fixed_end = off;

    // pick chunk length Tc (power of 2): xi chunk = 32*Tc*1536*2 bytes
    int Tc = 2048;
    if (ws_size > 0) {
        while (Tc > 128 &&
               fixed_end + (size_t)32 * Tc * 1536 * 2 > ws_size) Tc >>= 1;
    }
    int lgTc = 31 - __builtin_clz((u32)Tc);
    u16* xibuf = (u16*)take((size_t)32 * Tc * 1536 * 2);
    int nChunk = 2048 / Tc;

    // ---- prep ----
    transpose_cast<<<dim3(48, 8), 256, 0, stream>>>(Wi0, Wi0t, 256, 1536);
    transpose_cast<<<dim3(48, 16), 256, 0, stream>>>(Wi1, Wi1t, 512, 1536);
    pack_wh<<<384, 256, 0, stream>>>(Wh0, Wh0p);
    pack_wh<<<384, 256, 0, stream>>>(Wh1, Wh1p);

    // ---- layer 0 ----
    for (int c = 0; c < nChunk; ++c) {
        int t0 = c * Tc;
        gemm_xi<256, true><<<dim3(24, Tc / 2), 256, 0, stream>>>(
            (const void*)x, Wi0t, bi0, xibuf, t0, lgTc);
        const u16* xi_p = xibuf; const uint4* wh_p = Wh0p; const float* bh_p = bhn0;
        u64* hb_p = Hb0; u32* hs_p = (u32*)h0seq; float* h1_p = nullptr;
        float* st_p = hstate; int t0v = t0, Tcv = Tc, l0v = 1;
        void* args[] = {&xi_p, &wh_p, &bh_p, &hb_p, &hs_p, &h1_p, &st_p,
                        &t0v, &Tcv, &l0v};
        hipLaunchCooperativeKernel(gru_scan, dim3(256), dim3(512), args, 0, stream);
    }
    // ---- layer 1 ----
    for (int c = 0; c < nChunk; ++c) {
        int t0 = c * Tc;
        gemm_xi<512, false><<<dim3(24, Tc / 2), 256, 0, stream>>>(
            (const void*)h0seq, Wi1t, bi1, xibuf, t0, lgTc);
        const u16* xi_p = xibuf; const uint4* wh_p = Wh1p; const float* bh_p = bhn1;
        u64* hb_p = Hb1; u32* hs_p = nullptr; float* h1_p = h1last;
        float* st_p = hstate; int t0v = t0, Tcv = Tc, l0v = 0;
        void* args[] = {&xi_p, &wh_p, &bh_p, &hb_p, &hs_p, &h1_p, &st_p,
                        &t0v, &Tcv, &l0v};
        hipLaunchCooperativeKernel(gru_scan, dim3(256), dim3(512), args, 0, stream);
    }
    // ---- head ----
    final_fc<<<32, 64, 0, stream>>>(h1last, Wfc, bfc, out);
}